// Round 14
// baseline (296.467 us; speedup 1.0000x reference)
//
#include <hip/hip_runtime.h>
#include <hip/hip_bf16.h>
#include <stdint.h>

typedef __attribute__((ext_vector_type(8))) short short8_t;   // 8 bf16
typedef __attribute__((ext_vector_type(4))) float f32x4;
typedef __attribute__((ext_vector_type(4))) int   i32x4;

#define AS1 __attribute__((address_space(1)))
#define AS3 __attribute__((address_space(3)))

#define CB2_SHIFT 11
#define CBUCK2 2048                 // dst nodes per coarse bucket
#define FCHUNK 6144                 // edges per fill block
#define PADSLACK2 16384             // max per-segment pad (2048*7 < 16384)
#define NCHUNKS 4

__device__ __forceinline__ void gload_lds16(const void* g, void* l) {
    __builtin_amdgcn_global_load_lds((const AS1 unsigned int*)g,
                                     (AS3 unsigned int*)l, 16, 0, 0);
}

__device__ __forceinline__ unsigned short f2bf(float f) {
    unsigned int u = __float_as_uint(f);
    unsigned int r = (u + 0x7FFFu + ((u >> 16) & 1u)) >> 16;  // RNE
    return (unsigned short)r;
}

// ---------------- prep: cast h -> bf16 (+pad), Wt transpose, count, zrows ---
__global__ void prep_kernel(const float* __restrict__ h,
                            unsigned short* __restrict__ hb,
                            const float* __restrict__ w,
                            unsigned short* __restrict__ wt,
                            const int* __restrict__ dst,
                            const int* __restrict__ rel,
                            int* __restrict__ cnt,
                            unsigned int* __restrict__ z0,
                            unsigned int* __restrict__ z1,
                            int total4, int total4p, int castBlocks,
                            int R, int nE, int nseg2, int ncb, int rpc) {
    __shared__ int hist[128];
    const int b = blockIdx.x;
    if (b < castBlocks) {
        int t = b * 256 + threadIdx.x;
        if (t < total4) {
            float4 v = ((const float4*)h)[t];
            ushort4 o;
            o.x = f2bf(v.x); o.y = f2bf(v.y); o.z = f2bf(v.z); o.w = f2bf(v.w);
            *(ushort4*)(hb + (size_t)t * 4) = o;
        } else if (t < total4p) {
            *(ushort4*)(hb + (size_t)t * 4) = make_ushort4(0, 0, 0, 0);
        }
        return;
    }
    if (b < castBlocks + R) {
        int r = b - castBlocks;
        const float* wr = w + (size_t)r * 16384;
        unsigned short* wtr = wt + (size_t)r * 16384;
        for (int x = threadIdx.x; x < 16384; x += blockDim.x) {
            int i = x >> 7, o = x & 127;
            wtr[o * 128 + i] = f2bf(wr[x]);
        }
        return;
    }
    if (b < castBlocks + R + 256) {
        if (threadIdx.x < 128) hist[threadIdx.x] = 0;
        __syncthreads();
        int b2 = b - castBlocks - R;
        for (int e = b2 * 256 + threadIdx.x; e < nE; e += 65536) {
            int seg = (rel[e] / rpc) * ncb + (dst[e] >> CB2_SHIFT);
            atomicAdd(&hist[seg], 1);
        }
        __syncthreads();
        if (threadIdx.x < nseg2) {
            int v = hist[threadIdx.x];
            if (v) atomicAdd(cnt + threadIdx.x, v);
        }
        return;
    }
    if (threadIdx.x < 64) { z0[threadIdx.x] = 0u; z1[threadIdx.x] = 0u; }
}

// ---------------- fill: LDS-staged scatter into (chunk,cbucket) order -------
// entry: row(18) = rloc*NP+src | dloc(11)<<18   (requires rpc*NP < 2^18)
__global__ __launch_bounds__(256) void fill_staged_kernel(
    const int* __restrict__ src, const int* __restrict__ dst,
    const int* __restrict__ rel, const int* __restrict__ cnt,
    int* __restrict__ cur,
    int* __restrict__ packed, int nE, int nseg2, int ncb, int rpc, int np)
{
    __shared__ int stage[FCHUNK];
    __shared__ int hist[128], lscan[128], lcur[128], gbase[128], segb[128];
    const int tid = threadIdx.x;
    const int e0 = blockIdx.x * FCHUNK;
    const int e1 = min(nE, e0 + FCHUNK);

    if (tid < 128) {
        hist[tid] = 0;
        segb[tid] = (tid < nseg2) ? cnt[tid] : 0;
    }
    __syncthreads();
    for (int off = 1; off < 128; off <<= 1) {
        int t = 0;
        if (tid < 128 && tid >= off) t = segb[tid - off];
        __syncthreads();
        if (tid < 128) segb[tid] += t;
        __syncthreads();
    }
    if (tid < 128) segb[tid] -= (tid < nseg2) ? cnt[tid] : 0;   // exclusive

    for (int e = e0 + tid; e < e1; e += 256) {
        int seg = (rel[e] / rpc) * ncb + (dst[e] >> CB2_SHIFT);
        atomicAdd(&hist[seg], 1);
    }
    __syncthreads();

    if (tid < 128) lscan[tid] = hist[tid];
    __syncthreads();
    for (int off = 1; off < 128; off <<= 1) {
        int t = 0;
        if (tid < 128 && tid >= off) t = lscan[tid - off];
        __syncthreads();
        if (tid < 128) lscan[tid] += t;
        __syncthreads();
    }
    if (tid < 128) {
        int excl = lscan[tid] - hist[tid];
        lcur[tid] = excl;
        lscan[tid] = excl;
        gbase[tid] = segb[tid] +
            ((tid < nseg2 && hist[tid]) ? atomicAdd(cur + tid, hist[tid]) : 0);
    }
    __syncthreads();

    for (int e = e0 + tid; e < e1; e += 256) {
        int d = dst[e], r = rel[e];
        int chunk = r / rpc;
        int seg = chunk * ncb + (d >> CB2_SHIFT);
        int pk = ((r - chunk * rpc) * np + src[e]) | ((d & (CBUCK2 - 1)) << 18);
        int lp = atomicAdd(&lcur[seg], 1);
        stage[lp] = pk;
    }
    __syncthreads();

    const int wv = tid >> 6, lane = tid & 63;
    for (int s = wv; s < nseg2; s += 4) {
        int n = hist[s], from = lscan[s], to = gbase[s];
        for (int i = lane; i < n; i += 64)
            packed[to + i] = stage[from + i];
    }
}

// ---------------- mega: bin | gemm(chunk c) | gather(chunk c-1) -------------
__global__ __launch_bounds__(512, 4) void mega_kernel(
    int binBlocks, int gemmBlocks,
    // bin
    const int* __restrict__ cnt, const int* __restrict__ packed,
    int* __restrict__ packed2, int2* __restrict__ s2e2,
    int nseg2, int ncb, int zrow,
    // gemm
    const unsigned short* __restrict__ hb,   // [NP][128] bf16
    const unsigned short* __restrict__ wt,   // [R][128][128] bf16 (W^T)
    unsigned short* __restrict__ hwW,        // write buf [rpc*NP+1][128]
    int relBase, int rc, int np, int nwg,
    // gather
    const unsigned short* __restrict__ hwR,  // read buf (prev chunk)
    const float* __restrict__ bias,
    float* __restrict__ outp, float* __restrict__ agg,
    int n, int gchunk, int flags)
{
    __shared__ __align__(16) char smem[65536];
    const int tid = threadIdx.x;
    const int bid = blockIdx.x;

    if (bid < (unsigned)binBlocks) {
        // ---------------- bin: counting-sort segment by dst, pad to 8 -------
        int* hist = (int*)smem;            // [2048] counts -> later: end pos
        int* curp = hist + CBUCK2;         // [2048]
        int* aux  = curp + CBUCK2;         // [512]
        int* segb = aux + 512;             // [128]
        const int b2 = bid;
        const int chunk = b2 / ncb, cb = b2 - chunk * ncb;
        for (int i = tid; i < CBUCK2; i += 512) hist[i] = 0;
        if (tid < 128) segb[tid] = (tid < nseg2) ? cnt[tid] : 0;
        __syncthreads();
        for (int off = 1; off < 128; off <<= 1) {
            int t = 0;
            if (tid < 128 && tid >= off) t = segb[tid - off];
            __syncthreads();
            if (tid < 128) segb[tid] += t;
            __syncthreads();
        }
        const int e0 = segb[b2];
        const int s0 = e0 - cnt[b2];
        __syncthreads();
        for (int k = s0 + tid; k < e0; k += 512)
            atomicAdd(&hist[(packed[k] >> 18) & (CBUCK2 - 1)], 1);
        __syncthreads();
        const int base4 = tid * 4;
        int pc[4], ssum = 0;
#pragma unroll
        for (int j = 0; j < 4; ++j) {
            pc[j] = (hist[base4 + j] + 7) & ~7;
            ssum += pc[j];
        }
        aux[tid] = ssum;
        __syncthreads();
        int acc = ssum;
        for (int off = 1; off < 512; off <<= 1) {
            int t = (tid >= off) ? aux[tid - off] : 0;
            __syncthreads();
            acc += t; aux[tid] = acc;
            __syncthreads();
        }
        int run = s0 + b2 * PADSLACK2 + (acc - ssum);
#pragma unroll
        for (int j = 0; j < 4; ++j) {
            int node = (cb << CB2_SHIFT) + base4 + j;
            curp[base4 + j] = run;
            int endp = run + pc[j];
            if (node < n)
                s2e2[(size_t)chunk * n + node] = make_int2(run, endp);
            run = endp;
        }
        __syncthreads();
        // replace counts with end positions for the pad loop
#pragma unroll
        for (int j = 0; j < 4; ++j)
            hist[base4 + j] = curp[base4 + j] + pc[j];
        __syncthreads();
        for (int k = s0 + tid; k < e0; k += 512) {
            int pk = packed[k];
            int pos = atomicAdd(&curp[(pk >> 18) & (CBUCK2 - 1)], 1);
            packed2[pos] = pk & 0x3FFFF;
        }
        __syncthreads();
#pragma unroll
        for (int j = 0; j < 4; ++j) {
            int pend = hist[base4 + j];
            for (int p = curp[base4 + j]; p < pend; ++p) packed2[p] = zrow;
        }
        return;
    }

    if (bid < (unsigned)(binBlocks + gemmBlocks)) {
        // ---------------- gemm (round-8/13 proven one-shot 128x128) ---------
        char* ldsA = smem;
        char* ldsB = smem + 32768;
        const int lane = tid & 63;
        const int wv   = tid >> 6;
        const int wr   = wv >> 1;
        const int wc   = wv & 1;
        const int l15  = lane & 15, kb = lane >> 4;

        const int flat = bid - binBlocks;
        const int q = nwg >> 3, rm = nwg & 7;
        const int xcd = flat & 7, ii = flat >> 3;
        const int orig = (xcd < rm ? xcd * (q + 1) : rm * (q + 1) + (xcd - rm) * q) + ii;
        const int rloc = orig % rc;
        const int rowb = orig / rc;
        const int rel  = relBase + rloc;
        const size_t rowBase = (size_t)rowb * 128;

        const char* gA = (const char*)(hb + rowBase * 128);
        const char* gB = (const char*)(wt + (size_t)rel * 16384);

#pragma unroll
        for (int it = 0; it < 4; ++it) {
            int p = it * 8192 + tid * 16;
            int row = p >> 8;
            int so = (row << 8) + ((p & 255) ^ ((row & 7) << 4));
            gload_lds16(gA + so, ldsA + p);
            gload_lds16(gB + so, ldsB + p);
        }
        __syncthreads();

        f32x4 acc[2][4];
#pragma unroll
        for (int m = 0; m < 2; ++m)
#pragma unroll
            for (int nn = 0; nn < 4; ++nn) acc[m][nn] = (f32x4){0.f, 0.f, 0.f, 0.f};

#pragma unroll
        for (int kk = 0; kk < 4; ++kk) {
            short8_t a[2], b[4];
#pragma unroll
            for (int m = 0; m < 2; ++m) {
                int row = wr * 32 + m * 16 + l15;
                int byte = row * 256 + ((kk * 64 + kb * 16) ^ ((row & 7) << 4));
                a[m] = *(const short8_t*)(ldsA + byte);
            }
#pragma unroll
            for (int nn = 0; nn < 4; ++nn) {
                int row = wc * 64 + nn * 16 + l15;
                int byte = row * 256 + ((kk * 64 + kb * 16) ^ ((row & 7) << 4));
                b[nn] = *(const short8_t*)(ldsB + byte);
            }
#pragma unroll
            for (int m = 0; m < 2; ++m)
#pragma unroll
                for (int nn = 0; nn < 4; ++nn)
                    acc[m][nn] = __builtin_amdgcn_mfma_f32_16x16x32_bf16(
                        a[m], b[nn], acc[m][nn], 0, 0, 0);
        }

        __syncthreads();
#pragma unroll
        for (int m = 0; m < 2; ++m) {
#pragma unroll
            for (int nn = 0; nn < 4; ++nn) {
                int col = wc * 64 + nn * 16 + l15;
#pragma unroll
                for (int j = 0; j < 4; ++j) {
                    int row = wr * 32 + m * 16 + kb * 4 + j;
                    int byte = row * 256 + ((col * 2) ^ ((row & 7) << 4));
                    *(unsigned short*)(smem + byte) = f2bf(acc[m][nn][j]);
                }
            }
        }
        __syncthreads();

        char* gC = (char*)(hwW + ((size_t)rloc * np + rowBase) * 128);
#pragma unroll
        for (int j = 0; j < 4; ++j) {
            int p = j * 8192 + tid * 16;
            int row = p >> 8;
            i32x4 v = *(const i32x4*)(smem + row * 256 + ((p & 255) ^ ((row & 7) << 4)));
            *(i32x4*)(gC + p) = v;
        }
        return;
    }

    // ---------------- gather: 8 dsts/block (one per wave), no range check ---
    const int lane = tid & 63;
    const int wv   = tid >> 6;
    int wid = (bid - binBlocks - gemmBlocks) * 8 + wv;
    if (wid >= n) return;
    int2 se = s2e2[(size_t)gchunk * n + wid];
    int s = se.x, e = se.y;
    const bool mid = !(flags & 3);
    if (s == e && mid) return;                 // agg unchanged
    float a0 = 0.f, a1 = 0.f, a2 = 0.f, a3 = 0.f;
    const uint2* hw8 = (const uint2*)hwR;
    const int half = lane >> 5;
    const int c0 = lane & 31;

    for (int base = s; base < e; base += 64) {
        int m = e - base; if (m > 64) m = 64;
        int myp = (base + lane < e) ? packed2[base + lane] : zrow;
        for (int k = 0; k < m; k += 8) {
            uint2 v[4];
#pragma unroll
            for (int t = 0; t < 4; ++t) {
                int pe = __shfl(myp, k + 2 * t + half);
                v[t] = hw8[(size_t)pe * 32 + c0];
            }
#pragma unroll
            for (int t = 0; t < 4; ++t) {
                a0 += __uint_as_float(v[t].x << 16);
                a1 += __uint_as_float(v[t].x & 0xFFFF0000u);
                a2 += __uint_as_float(v[t].y << 16);
                a3 += __uint_as_float(v[t].y & 0xFFFF0000u);
            }
        }
    }
    a0 += __shfl_xor(a0, 32);
    a1 += __shfl_xor(a1, 32);
    a2 += __shfl_xor(a2, 32);
    a3 += __shfl_xor(a3, 32);

    if (lane < 32) {
        float4 acc4 = make_float4(a0, a1, a2, a3);
        float* ap = agg + (size_t)wid * 128 + c0 * 4;
        if (!(flags & 1)) {
            float4 p = *(const float4*)ap;
            acc4.x += p.x; acc4.y += p.y; acc4.z += p.z; acc4.w += p.w;
        }
        if (flags & 2) {
            float4 bv = *(const float4*)(bias + c0 * 4);
            float4 o;
            o.x = fmaxf(acc4.x + bv.x, 0.f);
            o.y = fmaxf(acc4.y + bv.y, 0.f);
            o.z = fmaxf(acc4.z + bv.z, 0.f);
            o.w = fmaxf(acc4.w + bv.w, 0.f);
            *(float4*)(outp + (size_t)wid * 128 + c0 * 4) = o;
        } else {
            *(float4*)ap = acc4;
        }
    }
}

static inline size_t align256(size_t x) { return (x + 255) & ~(size_t)255; }

extern "C" void kernel_launch(void* const* d_in, const int* in_sizes, int n_in,
                              void* d_out, int out_size, void* d_ws, size_t ws_size,
                              hipStream_t stream) {
    const float* h    = (const float*)d_in[0];
    const float* w    = (const float*)d_in[1];
    const float* bias = (const float*)d_in[2];
    const int*   src  = (const int*)d_in[3];
    const int*   dst  = (const int*)d_in[4];
    const int*   rel  = (const int*)d_in[5];
    float* out = (float*)d_out;

    const int N  = in_sizes[0] / 128;
    const int E  = in_sizes[3];
    const int R  = in_sizes[1] / (128 * 128);
    const int NB = (N + 127) / 128;
    const int NP = NB * 128;
    int CH = NCHUNKS; if (CH > R) CH = R;
    const int RPC = (R + CH - 1) / CH;          // rels per chunk
    const int NCB = (N + CBUCK2 - 1) >> CB2_SHIFT;
    const int nseg2 = CH * NCB;                 // <= 128 required
    const int ZROW = RPC * NP;                  // zero-row index (< 2^18)

    char* ws = (char*)d_ws;
    size_t off = 0;
    unsigned short* hb = (unsigned short*)(ws + off);
    off = align256(off + (size_t)NP * 128 * 2);
    unsigned short* wt = (unsigned short*)(ws + off);
    off = align256(off + (size_t)R * 16384 * 2);
    int* cntA = (int*)(ws + off);
    off = align256(off + 128 * 4);
    int* curA = (int*)(ws + off);
    off = align256(off + 128 * 4);
    int2* s2e2A = (int2*)(ws + off);
    off = align256(off + (size_t)CH * N * 8);
    int* packed = (int*)(ws + off);
    off = align256(off + (size_t)E * 4);
    int* packed2 = (int*)(ws + off);
    off = align256(off + ((size_t)E + (size_t)nseg2 * PADSLACK2 + 64) * 4);
    float* agg = (float*)(ws + off);
    off = align256(off + (size_t)N * 128 * 4);
    size_t bufB = align256(((size_t)RPC * NP + 1) * 128 * 2);
    unsigned short* buf0 = (unsigned short*)(ws + off); off += bufB;
    unsigned short* buf1 = (unsigned short*)(ws + off); off += bufB;
    // total ~140 MB; ws proven >= 230 MB in earlier fused-path rounds

    hipMemsetAsync(cntA, 0, align256(128 * 4) + 128 * 4, stream);

    int total4  = N * 32;
    int total4p = NP * 32;
    int castBlocks = (total4p + 255) / 256;
    int prepBlocks = castBlocks + R + 256 + 1;
    prep_kernel<<<prepBlocks, 256, 0, stream>>>(
        h, hb, w, wt, dst, rel, cntA,
        (unsigned int*)(buf0 + (size_t)ZROW * 128),
        (unsigned int*)(buf1 + (size_t)ZROW * 128),
        total4, total4p, castBlocks, R, E, nseg2, NCB, RPC);

    fill_staged_kernel<<<(E + FCHUNK - 1) / FCHUNK, 256, 0, stream>>>(
        src, dst, rel, cntA, curA, packed, E, nseg2, NCB, RPC, NP);

    unsigned short* bufs[2] = {buf0, buf1};
    const int gatherBlocks = (N + 7) / 8;
    for (int c = 0; c <= CH; ++c) {
        int rcC   = (c < CH) ? ((R - c * RPC < RPC) ? (R - c * RPC) : RPC) : 0;
        int gemmB = (c < CH) ? NB * rcC : 0;
        int binB  = (c == 0) ? nseg2 : 0;
        int gB    = (c > 0) ? gatherBlocks : 0;
        int gchunk = c - 1;
        int flags = (gchunk == 0 ? 1 : 0) | (gchunk == CH - 1 ? 2 : 0);
        mega_kernel<<<binB + gemmB + gB, 512, 0, stream>>>(
            binB, gemmB,
            cntA, packed, packed2, s2e2A, nseg2, NCB, ZROW,
            hb, wt, bufs[c & 1], c * RPC, rcC < 1 ? 1 : rcC, NP, gemmB,
            bufs[(c > 0 ? gchunk : 0) & 1], bias, out, agg, N,
            gchunk < 0 ? 0 : gchunk, flags);
    }
}

// Round 15
// 187.746 us; speedup vs baseline: 1.5791x; 1.5791x over previous
//
#include <hip/hip_runtime.h>
#include <hip/hip_bf16.h>
#include <stdint.h>

typedef __attribute__((ext_vector_type(8))) short short8_t;   // 8 bf16
typedef __attribute__((ext_vector_type(4))) float f32x4;
typedef __attribute__((ext_vector_type(4))) int   i32x4;

#define AS1 __attribute__((address_space(1)))
#define AS3 __attribute__((address_space(3)))

#define CB_SHIFT 9
#define CBUCK 512                   // dst nodes per coarse bucket
#define FCHUNK 6144                 // edges per fill block
#define PADSLACK 4096               // max per-bucket pad (512*7 < 4096)

__device__ __forceinline__ void gload_lds16(const void* g, void* l) {
    __builtin_amdgcn_global_load_lds((const AS1 unsigned int*)g,
                                     (AS3 unsigned int*)l, 16, 0, 0);
}

__device__ __forceinline__ unsigned short f2bf(float f) {
    unsigned int u = __float_as_uint(f);
    unsigned int r = (u + 0x7FFFu + ((u >> 16) & 1u)) >> 16;  // RNE
    return (unsigned short)r;
}

// ---------------- prep: bucket count + zero-row (cast/wt moved to fill) -----
__global__ void prep_kernel(const int* __restrict__ dst,
                            int* __restrict__ cnt,
                            unsigned int* __restrict__ zrow,
                            int nE, int nseg) {
    __shared__ int hist[128];
    const int b = blockIdx.x;
    if (b < 256) {
        if (threadIdx.x < 128) hist[threadIdx.x] = 0;
        __syncthreads();
        for (int e = b * 256 + threadIdx.x; e < nE; e += 65536)
            atomicAdd(&hist[dst[e] >> CB_SHIFT], 1);
        __syncthreads();
        if (threadIdx.x < nseg) {
            int v = hist[threadIdx.x];
            if (v) atomicAdd(cnt + threadIdx.x, v);
        }
        return;
    }
    if (threadIdx.x < 64) zrow[threadIdx.x] = 0u;   // 256 B bf16 zero row
}

// ---------------- merged: bin (first binBlocks) + GEMM (rest) ---------------
// gemm: one-shot 128x128 bf16 MFMA, nt stores for hw (HBM round-trip proven).
__global__ __launch_bounds__(512, 4) void binGemm_kernel(
    // bin args
    const int* __restrict__ cnt, const int* __restrict__ packed,
    int* __restrict__ packed2, int2* __restrict__ s2e2,
    int nseg, int zrow, int binBlocks,
    // gemm args
    const unsigned short* __restrict__ hb,   // [NP][128] bf16
    const unsigned short* __restrict__ wt,   // [R][128][128] bf16 (W^T)
    unsigned short* __restrict__ hw,         // [RC][NP][128] bf16 (+ zero row)
    int r0, int rc, int np, int nwg)
{
    __shared__ __align__(16) char smem[65536];
    const int tid = threadIdx.x;

    if (blockIdx.x < (unsigned)binBlocks) {
        // ---------------- bin: counting-sort bucket by dst, pad to 8 --------
        int* hist = (int*)smem;           // [512]
        int* pscn = hist + CBUCK;         // [512]
        int* cur  = pscn + CBUCK;         // [512]
        int* segb = cur + CBUCK;          // [128]
        const int b = blockIdx.x;
        if (tid < 128) segb[tid] = (tid < nseg) ? cnt[tid] : 0;
        hist[tid] = 0;  // tid < 512 == CBUCK
        __syncthreads();
        for (int off = 1; off < 128; off <<= 1) {
            int t = 0;
            if (tid < 128 && tid >= off) t = segb[tid - off];
            __syncthreads();
            if (tid < 128) segb[tid] += t;
            __syncthreads();
        }
        const int e0 = segb[b];
        const int s0 = e0 - cnt[b];
        for (int k = s0 + tid; k < e0; k += 512)
            atomicAdd(&hist[(packed[k] >> 20) & (CBUCK - 1)], 1);
        __syncthreads();
        int pc = (hist[tid] + 7) & ~7;
        pscn[tid] = pc;
        __syncthreads();
        for (int off = 1; off < CBUCK; off <<= 1) {
            int t = (tid >= off) ? pscn[tid - off] : 0;
            __syncthreads();
            pscn[tid] += t;
            __syncthreads();
        }
        const int pbase = s0 + b * PADSLACK;
        int ps = pbase + pscn[tid] - pc;
        cur[tid] = ps;
        s2e2[(size_t)b * CBUCK + tid] = make_int2(ps, ps + pc);
        __syncthreads();
        for (int k = s0 + tid; k < e0; k += 512) {
            int pk = packed[k];
            int pos = atomicAdd(&cur[(pk >> 20) & (CBUCK - 1)], 1);
            packed2[pos] = pk;
        }
        __syncthreads();
        int pend = ps + pc;
        for (int p = cur[tid]; p < pend; ++p) packed2[p] = zrow;
        return;
    }

    // ---------------- gemm ----------------
    char* ldsA = smem;
    char* ldsB = smem + 32768;
    const int lane = tid & 63;
    const int wv   = tid >> 6;
    const int wr   = wv >> 1;           // 0..3
    const int wc   = wv & 1;            // 0..1
    const int l15  = lane & 15, kb = lane >> 4;

    const int flat = blockIdx.x - binBlocks;
    const int q = nwg >> 3, rm = nwg & 7;
    const int xcd = flat & 7, ii = flat >> 3;
    const int orig = (xcd < rm ? xcd * (q + 1) : rm * (q + 1) + (xcd - rm) * q) + ii;
    const int rloc = orig % rc;
    const int rowb = orig / rc;
    const int rel  = r0 + rloc;
    const size_t rowBase = (size_t)rowb * 128;

    const char* gA = (const char*)(hb + rowBase * 128);
    const char* gB = (const char*)(wt + (size_t)rel * 16384);

#pragma unroll
    for (int it = 0; it < 4; ++it) {
        int p = it * 8192 + tid * 16;
        int row = p >> 8;
        int so = (row << 8) + ((p & 255) ^ ((row & 7) << 4));
        gload_lds16(gA + so, ldsA + p);
        gload_lds16(gB + so, ldsB + p);
    }
    __syncthreads();

    f32x4 acc[2][4];
#pragma unroll
    for (int m = 0; m < 2; ++m)
#pragma unroll
        for (int n = 0; n < 4; ++n) acc[m][n] = (f32x4){0.f, 0.f, 0.f, 0.f};

#pragma unroll
    for (int kk = 0; kk < 4; ++kk) {
        short8_t a[2], b[4];
#pragma unroll
        for (int m = 0; m < 2; ++m) {
            int row = wr * 32 + m * 16 + l15;
            int byte = row * 256 + ((kk * 64 + kb * 16) ^ ((row & 7) << 4));
            a[m] = *(const short8_t*)(ldsA + byte);
        }
#pragma unroll
        for (int n = 0; n < 4; ++n) {
            int row = wc * 64 + n * 16 + l15;
            int byte = row * 256 + ((kk * 64 + kb * 16) ^ ((row & 7) << 4));
            b[n] = *(const short8_t*)(ldsB + byte);
        }
#pragma unroll
        for (int m = 0; m < 2; ++m)
#pragma unroll
            for (int n = 0; n < 4; ++n)
                acc[m][n] = __builtin_amdgcn_mfma_f32_16x16x32_bf16(
                    a[m], b[n], acc[m][n], 0, 0, 0);
    }

    __syncthreads();
#pragma unroll
    for (int m = 0; m < 2; ++m) {
#pragma unroll
        for (int n = 0; n < 4; ++n) {
            int col = wc * 64 + n * 16 + l15;
#pragma unroll
            for (int j = 0; j < 4; ++j) {
                int row = wr * 32 + m * 16 + kb * 4 + j;
                int byte = row * 256 + ((col * 2) ^ ((row & 7) << 4));
                *(unsigned short*)(smem + byte) = f2bf(acc[m][n][j]);
            }
        }
    }
    __syncthreads();

    char* gC = (char*)(hw + ((size_t)rloc * np + rowBase) * 128);
#pragma unroll
    for (int j = 0; j < 4; ++j) {
        int p = j * 8192 + tid * 16;
        int row = p >> 8;
        i32x4 v = *(const i32x4*)(smem + row * 256 + ((p & 255) ^ ((row & 7) << 4)));
        __builtin_nontemporal_store(v, (i32x4*)(gC + p));
    }
}

// ---------------- fill (+cast h, +Wt transpose as leading block ranges) -----
// entry: rowIdx(20) = rel*NP+src | dloc(9)<<20   (requires R*NP < 2^20)
__global__ __launch_bounds__(256) void fillcast_kernel(
    const float* __restrict__ h, unsigned short* __restrict__ hb,
    const float* __restrict__ w, unsigned short* __restrict__ wtp,
    int total4, int total4p, int castBlocks, int R,
    const int* __restrict__ src, const int* __restrict__ dst,
    const int* __restrict__ rel, const int* __restrict__ cnt,
    int* __restrict__ cur,
    int* __restrict__ packed, int nE, int nseg, int np)
{
    __shared__ int stage[FCHUNK];
    __shared__ int hist[128], lscan[128], lcur[128], gbase[128], segb[128];
    const int tid = threadIdx.x;
    const int b = blockIdx.x;

    if (b < castBlocks) {                       // cast h -> bf16 (+pad)
        int t = b * 256 + tid;
        if (t < total4) {
            float4 v = ((const float4*)h)[t];
            ushort4 o;
            o.x = f2bf(v.x); o.y = f2bf(v.y); o.z = f2bf(v.z); o.w = f2bf(v.w);
            *(ushort4*)(hb + (size_t)t * 4) = o;
        } else if (t < total4p) {
            *(ushort4*)(hb + (size_t)t * 4) = make_ushort4(0, 0, 0, 0);
        }
        return;
    }
    if (b < castBlocks + R) {                   // Wt transpose
        int r = b - castBlocks;
        const float* wr = w + (size_t)r * 16384;
        unsigned short* wtr = wtp + (size_t)r * 16384;
        for (int x = tid; x < 16384; x += 256) {
            int i = x >> 7, o = x & 127;
            wtr[o * 128 + i] = f2bf(wr[x]);
        }
        return;
    }

    const int e0 = (b - castBlocks - R) * FCHUNK;
    const int e1 = min(nE, e0 + FCHUNK);

    if (tid < 128) {
        hist[tid] = 0;
        segb[tid] = (tid < nseg) ? cnt[tid] : 0;
    }
    __syncthreads();
    for (int off = 1; off < 128; off <<= 1) {
        int t = 0;
        if (tid < 128 && tid >= off) t = segb[tid - off];
        __syncthreads();
        if (tid < 128) segb[tid] += t;
        __syncthreads();
    }
    if (tid < 128) segb[tid] -= (tid < nseg) ? cnt[tid] : 0;   // exclusive

    for (int e = e0 + tid; e < e1; e += 256)
        atomicAdd(&hist[dst[e] >> CB_SHIFT], 1);
    __syncthreads();

    if (tid < 128) lscan[tid] = hist[tid];
    __syncthreads();
    for (int off = 1; off < 128; off <<= 1) {
        int t = 0;
        if (tid < 128 && tid >= off) t = lscan[tid - off];
        __syncthreads();
        if (tid < 128) lscan[tid] += t;
        __syncthreads();
    }
    if (tid < 128) {
        int excl = lscan[tid] - hist[tid];
        lcur[tid] = excl;
        lscan[tid] = excl;
        gbase[tid] = segb[tid] +
            ((tid < nseg && hist[tid]) ? atomicAdd(cur + tid, hist[tid]) : 0);
    }
    __syncthreads();

    for (int e = e0 + tid; e < e1; e += 256) {
        int d = dst[e];
        int seg = d >> CB_SHIFT;
        int pk = (rel[e] * np + src[e]) | ((d & (CBUCK - 1)) << 20);
        int lp = atomicAdd(&lcur[seg], 1);
        stage[lp] = pk;
    }
    __syncthreads();

    const int wv = tid >> 6, lane = tid & 63;
    for (int s = wv; s < nseg; s += 4) {
        int n = hist[s], from = lscan[s], to = gbase[s];
        for (int i = lane; i < n; i += 64)
            packed[to + i] = stage[from + i];
    }
}

// ---------------- gather2: one wave per dst, 8B/lane, padded segments -------
__global__ __launch_bounds__(256) void gather2_kernel(
    const unsigned short* __restrict__ hw,
    const int2* __restrict__ s2e2,
    const int* __restrict__ packed2,
    const float* __restrict__ bias,
    float* __restrict__ outp, float* __restrict__ agg,
    int n, int r0np, int rcnp, int zrl, int flags /*1=first,2=last*/)
{
    int wid  = (blockIdx.x * blockDim.x + threadIdx.x) >> 6;
    int lane = threadIdx.x & 63;
    if (wid >= n) return;
    int2 se = s2e2[wid];
    int s = se.x, e = se.y;
    float a0 = 0.f, a1 = 0.f, a2 = 0.f, a3 = 0.f;
    const uint2* hw8 = (const uint2*)hw;
    const int half = lane >> 5;
    const int c0 = lane & 31;

    for (int base = s; base < e; base += 64) {
        int m = e - base; if (m > 64) m = 64;
        int myp = (base + lane < e) ? packed2[base + lane] : 0;
        for (int k = 0; k < m; k += 8) {
            uint2 v[4];
#pragma unroll
            for (int t = 0; t < 4; ++t) {
                int pe = __shfl(myp, k + 2 * t + half);
                int rl = (pe & 0xFFFFF) - r0np;
                if ((unsigned)rl >= (unsigned)rcnp) rl = zrl;
                v[t] = hw8[(size_t)rl * 32 + c0];
            }
#pragma unroll
            for (int t = 0; t < 4; ++t) {
                a0 += __uint_as_float(v[t].x << 16);
                a1 += __uint_as_float(v[t].x & 0xFFFF0000u);
                a2 += __uint_as_float(v[t].y << 16);
                a3 += __uint_as_float(v[t].y & 0xFFFF0000u);
            }
        }
    }
    a0 += __shfl_xor(a0, 32);
    a1 += __shfl_xor(a1, 32);
    a2 += __shfl_xor(a2, 32);
    a3 += __shfl_xor(a3, 32);

    if (lane < 32) {
        float4 acc4 = make_float4(a0, a1, a2, a3);
        float* ap = agg + (size_t)wid * 128 + c0 * 4;
        if (!(flags & 1)) {
            float4 p = *(const float4*)ap;
            acc4.x += p.x; acc4.y += p.y; acc4.z += p.z; acc4.w += p.w;
        }
        if (flags & 2) {
            float4 bv = *(const float4*)(bias + c0 * 4);
            float4 o;
            o.x = fmaxf(acc4.x + bv.x, 0.f);
            o.y = fmaxf(acc4.y + bv.y, 0.f);
            o.z = fmaxf(acc4.z + bv.z, 0.f);
            o.w = fmaxf(acc4.w + bv.w, 0.f);
            *(float4*)(outp + (size_t)wid * 128 + c0 * 4) = o;
        } else {
            *(float4*)ap = acc4;
        }
    }
}

static inline size_t align256(size_t x) { return (x + 255) & ~(size_t)255; }

extern "C" void kernel_launch(void* const* d_in, const int* in_sizes, int n_in,
                              void* d_out, int out_size, void* d_ws, size_t ws_size,
                              hipStream_t stream) {
    const float* h    = (const float*)d_in[0];
    const float* w    = (const float*)d_in[1];
    const float* bias = (const float*)d_in[2];
    const int*   src  = (const int*)d_in[3];
    const int*   dst  = (const int*)d_in[4];
    const int*   rel  = (const int*)d_in[5];
    float* out = (float*)d_out;

    const int N  = in_sizes[0] / 128;
    const int E  = in_sizes[3];
    const int R  = in_sizes[1] / (128 * 128);  // requires R*NP < 2^20
    const int NB = (N + 127) / 128;
    const int NP = NB * 128;
    const int NSEG = (N + CBUCK - 1) >> CB_SHIFT;

    char* ws = (char*)d_ws;
    size_t off = 0;
    unsigned short* hb = (unsigned short*)(ws + off);
    off = align256(off + (size_t)NP * 128 * 2);
    unsigned short* wt = (unsigned short*)(ws + off);
    off = align256(off + (size_t)R * 16384 * 2);
    int* cntA = (int*)(ws + off);
    off = align256(off + 128 * 4);
    int* curA = (int*)(ws + off);
    off = align256(off + 128 * 4);
    int2* s2e2A = (int2*)(ws + off);
    off = align256(off + (size_t)NSEG * CBUCK * 8);
    int* packed = (int*)(ws + off);
    off = align256(off + (size_t)E * 4);
    int* packed2 = (int*)(ws + off);
    off = align256(off + ((size_t)E + (size_t)NSEG * PADSLACK + 64) * 4);
    size_t fixed = off;

    size_t perRel = (size_t)NP * 128 * 2;      // bf16: 2 B/elem
    size_t aggB   = (size_t)N * 128 * 4;
    size_t avail  = ws_size > fixed ? ws_size - fixed : 0;

    int RC, fused; float* agg; unsigned short* hwb;
    if (avail >= (size_t)R * perRel + 256) {
        RC = R; fused = 1;
        hwb = (unsigned short*)(ws + fixed);
        agg = (float*)(ws + fixed);     // unused when fused
    } else {
        fused = 0;
        agg = (float*)(ws + fixed);
        size_t a2 = avail > aggB + 256 ? avail - aggB - 256 : 0;
        RC = (int)(a2 / perRel);
        if (RC > R) RC = R;
        if (RC < 1) RC = 1;
        hwb = (unsigned short*)(ws + align256(fixed + aggB));
    }

    // zero counts + cursors (contiguous, 256-aligned each)
    hipMemsetAsync(cntA, 0, align256(128 * 4) + 128 * 4, stream);

    // prep: bucket count + bf16 zero row
    prep_kernel<<<257, 256, 0, stream>>>(
        dst, cntA, (unsigned int*)(hwb + (size_t)RC * NP * 128), E, NSEG);

    // fill + cast h + Wt transpose (independent block ranges)
    int total4  = N * 32;
    int total4p = NP * 32;
    int castBlocks = (total4p + 255) / 256;
    int fillBlocks = (E + FCHUNK - 1) / FCHUNK;
    fillcast_kernel<<<castBlocks + R + fillBlocks, 256, 0, stream>>>(
        h, hb, w, wt, total4, total4p, castBlocks, R,
        src, dst, rel, cntA, curA, packed, E, NSEG, NP);

    int gblocks = (N * 64 + 255) / 256;
    for (int r0 = 0; r0 < R; r0 += RC) {
        int rc = (R - r0 < RC) ? (R - r0) : RC;
        int nwg = NB * rc;
        int binBlocks = (r0 == 0) ? NSEG : 0;
        binGemm_kernel<<<binBlocks + nwg, 512, 0, stream>>>(
            cntA, packed, packed2, s2e2A, NSEG, R * NP, binBlocks,
            hb, wt, hwb, r0, rc, NP, nwg);
        int flags = (r0 == 0 ? 1 : 0) | (r0 + rc >= R ? 2 : 0);
        gather2_kernel<<<gblocks, 256, 0, stream>>>(hwb, s2e2A, packed2, bias,
                                                    out, agg, N, r0 * NP,
                                                    rc * NP, RC * NP,
                                                    fused ? 3 : flags);
    }
}